// Round 8
// baseline (179.955 us; speedup 1.0000x reference)
//
#include <hip/hip_runtime.h>
#include <math.h>

#define NXC 200    // grid edge
#define NBB 512    // batch
#define TPB 1024   // threads per block (16 waves)
#define NACT 1000  // active threads in the streaming loop

// One block per batch (512 blocks). Same verified structure as round 7
// (index algebra, single-writer LDS partials, epilogue all identical,
// absmax=0), with ONE change: each pass issues all 10 independent float4
// loads into NAMED registers, then a sched_barrier(0) fence, then consumes.
// The fence pins 10 loads in flight per thread (round-7 post-mortem: the
// compiler kept only ~2-3 in flight, VGPR=28 -- deep MLP never happened).
//
// Index algebra: thread t<1000 reads f = t + 1000k, k=0..9.
//   quad  c = t mod 50 (static), row = t/50 + 20k = a + 20k (static per k)
// -> col sums in 4 named registers; row quad-partials are single-writer LDS
//    stores; heat and layout are two sequential passes sharing buffers.
__global__ __launch_bounds__(TPB) void heat_loss_kernel(
    const float* __restrict__ layout, const float* __restrict__ heat,
    float* __restrict__ out) {
  const int b    = blockIdx.x;
  const int tid  = threadIdx.x;
  const int wave = tid >> 6;
  const int lane = tid & 63;

  __shared__ __align__(16) float4 s_colp[20][50];  // col-quad partials (16 KB)
  __shared__ float s_rowp[NXC][51];  // row-quad partials, pad 51
  __shared__ float s_CS[NXC];        // column sums heat
  __shared__ float s_CL[NXC];        // column sums layout
  __shared__ float s_RS[NXC];        // row sums heat
  __shared__ float s_RL[NXC];        // row sums layout
  __shared__ float s_red[4][16];     // minv/maxv/minh/maxh per wave
  __shared__ float s_sum[16];        // contrib partial per wave

  const float4* __restrict__ hp =
      reinterpret_cast<const float4*>(heat + (size_t)b * NXC * NXC);
  const float4* __restrict__ lp =
      reinterpret_cast<const float4*>(layout + (size_t)b * NXC * NXC);

  const int a = tid / 50;   // 0..19 for active threads
  const int c = tid % 50;

  // ---------------- pass 1: heat ----------------
  if (tid < NACT) {
    // issue ALL 10 loads back-to-back (independent addresses, named regs)
    const float4 v0 = hp[tid +    0];
    const float4 v1 = hp[tid + 1000];
    const float4 v2 = hp[tid + 2000];
    const float4 v3 = hp[tid + 3000];
    const float4 v4 = hp[tid + 4000];
    const float4 v5 = hp[tid + 5000];
    const float4 v6 = hp[tid + 6000];
    const float4 v7 = hp[tid + 7000];
    const float4 v8 = hp[tid + 8000];
    const float4 v9 = hp[tid + 9000];
    __builtin_amdgcn_sched_barrier(0);  // loads may not sink below this point

    s_rowp[a +   0][c] = (v0.x + v0.y) + (v0.z + v0.w);
    s_rowp[a +  20][c] = (v1.x + v1.y) + (v1.z + v1.w);
    s_rowp[a +  40][c] = (v2.x + v2.y) + (v2.z + v2.w);
    s_rowp[a +  60][c] = (v3.x + v3.y) + (v3.z + v3.w);
    s_rowp[a +  80][c] = (v4.x + v4.y) + (v4.z + v4.w);
    s_rowp[a + 100][c] = (v5.x + v5.y) + (v5.z + v5.w);
    s_rowp[a + 120][c] = (v6.x + v6.y) + (v6.z + v6.w);
    s_rowp[a + 140][c] = (v7.x + v7.y) + (v7.z + v7.w);
    s_rowp[a + 160][c] = (v8.x + v8.y) + (v8.z + v8.w);
    s_rowp[a + 180][c] = (v9.x + v9.y) + (v9.z + v9.w);

    const float cs0 = (((v0.x + v1.x) + (v2.x + v3.x)) +
                       ((v4.x + v5.x) + (v6.x + v7.x))) + (v8.x + v9.x);
    const float cs1 = (((v0.y + v1.y) + (v2.y + v3.y)) +
                       ((v4.y + v5.y) + (v6.y + v7.y))) + (v8.y + v9.y);
    const float cs2 = (((v0.z + v1.z) + (v2.z + v3.z)) +
                       ((v4.z + v5.z) + (v6.z + v7.z))) + (v8.z + v9.z);
    const float cs3 = (((v0.w + v1.w) + (v2.w + v3.w)) +
                       ((v4.w + v5.w) + (v6.w + v7.w))) + (v8.w + v9.w);
    s_colp[a][c] = make_float4(cs0, cs1, cs2, cs3);
  }
  __syncthreads();

  if (tid < NXC) {
    const float* cp = (const float*)s_colp;  // [a][200] flat view
    float s = 0.f;
    #pragma unroll
    for (int a2 = 0; a2 < 20; ++a2) s += cp[a2 * 200 + tid];
    float r = 0.f;
    #pragma unroll
    for (int m = 0; m < 50; ++m) r += s_rowp[tid][m];
    s_CS[tid] = s; s_RS[tid] = r;
  }
  __syncthreads();  // partial buffers now reusable

  // ---------------- pass 2: layout ----------------
  if (tid < NACT) {
    const float4 v0 = lp[tid +    0];
    const float4 v1 = lp[tid + 1000];
    const float4 v2 = lp[tid + 2000];
    const float4 v3 = lp[tid + 3000];
    const float4 v4 = lp[tid + 4000];
    const float4 v5 = lp[tid + 5000];
    const float4 v6 = lp[tid + 6000];
    const float4 v7 = lp[tid + 7000];
    const float4 v8 = lp[tid + 8000];
    const float4 v9 = lp[tid + 9000];
    __builtin_amdgcn_sched_barrier(0);

    s_rowp[a +   0][c] = (v0.x + v0.y) + (v0.z + v0.w);
    s_rowp[a +  20][c] = (v1.x + v1.y) + (v1.z + v1.w);
    s_rowp[a +  40][c] = (v2.x + v2.y) + (v2.z + v2.w);
    s_rowp[a +  60][c] = (v3.x + v3.y) + (v3.z + v3.w);
    s_rowp[a +  80][c] = (v4.x + v4.y) + (v4.z + v4.w);
    s_rowp[a + 100][c] = (v5.x + v5.y) + (v5.z + v5.w);
    s_rowp[a + 120][c] = (v6.x + v6.y) + (v6.z + v6.w);
    s_rowp[a + 140][c] = (v7.x + v7.y) + (v7.z + v7.w);
    s_rowp[a + 160][c] = (v8.x + v8.y) + (v8.z + v8.w);
    s_rowp[a + 180][c] = (v9.x + v9.y) + (v9.z + v9.w);

    const float cs0 = (((v0.x + v1.x) + (v2.x + v3.x)) +
                       ((v4.x + v5.x) + (v6.x + v7.x))) + (v8.x + v9.x);
    const float cs1 = (((v0.y + v1.y) + (v2.y + v3.y)) +
                       ((v4.y + v5.y) + (v6.y + v7.y))) + (v8.y + v9.y);
    const float cs2 = (((v0.z + v1.z) + (v2.z + v3.z)) +
                       ((v4.z + v5.z) + (v6.z + v7.z))) + (v8.z + v9.z);
    const float cs3 = (((v0.w + v1.w) + (v2.w + v3.w)) +
                       ((v4.w + v5.w) + (v6.w + v7.w))) + (v8.w + v9.w);
    s_colp[a][c] = make_float4(cs0, cs1, cs2, cs3);
  }
  __syncthreads();

  if (tid < NXC) {
    const float* cp = (const float*)s_colp;
    float s = 0.f;
    #pragma unroll
    for (int a2 = 0; a2 < 20; ++a2) s += cp[a2 * 200 + tid];
    float r = 0.f;
    #pragma unroll
    for (int m = 0; m < 50; ++m) r += s_rowp[tid][m];
    s_CL[tid] = s; s_RL[tid] = r;
  }
  __syncthreads();

  // ---------------- epilogue (verified exact in rounds 1-7) ----------------
  const float* __restrict__ hb = heat + (size_t)b * NXC * NXC;
  const float COF = (float)(0.25 * (0.1 / 199.0) * (0.1 / 199.0));
  float dv = 0.f, dh = 0.f;
  if (tid < NXC) {
    const int j  = tid;
    const int jm = (j == 0) ? 1 : j - 1;
    const int jp = (j == NXC - 1) ? NXC - 2 : j + 1;

    // boundary rows 0,1,198,199 (coalesced, L2-hot re-reads)
    const float h0   = hb[0 * NXC + j];
    const float h1   = hb[1 * NXC + j];
    const float h198 = hb[198 * NXC + j];
    const float h199 = hb[199 * NXC + j];
    float Sv = 0.25f * (2.f * s_CS[j]
                        + h1 - h199        // +h[1,j]   - h[199,j]
                        + h198 - h0        // +h[198,j] - h[0,j]
                        + s_CS[jm] + s_CS[jp])
             + COF * s_CL[j];
    dv = fabsf(Sv - s_CS[j]) * (1.f / NXC);

    // boundary cols 0,1,198,199 of row j via two aligned float4 loads
    const float4 c03 = *reinterpret_cast<const float4*>(hb + (size_t)j * NXC);
    const float4 c69 = *reinterpret_cast<const float4*>(hb + (size_t)j * NXC + 196);
    float Sh = 0.25f * (2.f * s_RS[j]
                        + c03.y - c69.w    // +h[j,1]   - h[j,199]
                        + c69.z - c03.x    // +h[j,198] - h[j,0]
                        + s_RS[jm] + s_RS[jp])
             + COF * s_RL[j];
    dh = fabsf(Sh - s_RS[j]) * (1.f / NXC);
  }

  // per-batch min/max of dv and dh (dv,dh >= 0 so max pad 0 is safe)
  float mnv = (tid < NXC) ? dv : INFINITY;
  float mxv = dv;
  float mnh = (tid < NXC) ? dh : INFINITY;
  float mxh = dh;
  #pragma unroll
  for (int off = 32; off > 0; off >>= 1) {
    mnv = fminf(mnv, __shfl_down(mnv, off));
    mxv = fmaxf(mxv, __shfl_down(mxv, off));
    mnh = fminf(mnh, __shfl_down(mnh, off));
    mxh = fmaxf(mxh, __shfl_down(mxh, off));
  }
  if (lane == 0) {
    s_red[0][wave] = mnv;
    s_red[1][wave] = mxv;
    s_red[2][wave] = mnh;
    s_red[3][wave] = mxh;
  }
  __syncthreads();

  float MNV = INFINITY, MXV = -INFINITY, MNH = INFINITY, MXH = -INFINITY;
  #pragma unroll
  for (int w = 0; w < 16; ++w) {
    MNV = fminf(MNV, s_red[0][w]); MXV = fmaxf(MXV, s_red[1][w]);
    MNH = fminf(MNH, s_red[2][w]); MXH = fmaxf(MXH, s_red[3][w]);
  }

  float contrib = 0.f;
  if (tid < NXC) {
    contrib = 10.f * (dv - MNV) * dv / (MXV - MNV)
            + 10.f * (dh - MNH) * dh / (MXH - MNH);
  }
  #pragma unroll
  for (int off = 32; off > 0; off >>= 1) contrib += __shfl_down(contrib, off);
  if (lane == 0) s_sum[wave] = contrib;
  __syncthreads();
  if (tid == 0) {
    float tot = 0.f;
    #pragma unroll
    for (int w = 0; w < 16; ++w) tot += s_sum[w];
    atomicAdd(out, tot * (1.f / ((float)NBB * (float)NXC)));
  }
}

extern "C" void kernel_launch(void* const* d_in, const int* in_sizes, int n_in,
                              void* d_out, int out_size, void* d_ws, size_t ws_size,
                              hipStream_t stream) {
  const float* layout = (const float*)d_in[0];
  const float* heat   = (const float*)d_in[1];
  float* out = (float*)d_out;

  // d_out is poisoned to 0xAA before every timed launch — zero it first.
  hipMemsetAsync(out, 0, (size_t)out_size * sizeof(float), stream);
  heat_loss_kernel<<<NBB, TPB, 0, stream>>>(layout, heat, out);
}

// Round 9
// 171.725 us; speedup vs baseline: 1.0479x; 1.0479x over previous
//
#include <hip/hip_runtime.h>
#include <math.h>

#define NXC 200    // grid edge
#define NBB 512    // batch
#define TPB 1024   // threads per block (16 waves)
#define NACT 1000  // active threads in the streaming loop

typedef float f4 __attribute__((ext_vector_type(4)));

// One block per batch (512 blocks). Identical verified structure to round 8
// (index algebra, single-writer LDS partials, epilogue; absmax=0), with ONE
// change: the 20 streaming loads are NON-TEMPORAL (evict-first / no LLC
// allocation). Theory: the ~2.6 TB/s plateau seen by four clean structures
// is the Infinity-Cache hit-service rate on the persistent ~46% resident
// mix (FETCH=88.7 of 164 MB); NT decays residency across bench iterations,
// converting to pure HBM streaming (m13 regime: 6.3 TB/s).
//
// Index algebra: thread t<1000 reads f = t + 1000k, k=0..9.
//   quad  c = t mod 50 (static), row = t/50 + 20k = a + 20k (static per k)
// -> col sums in 4 named registers; row quad-partials are single-writer LDS
//    stores; heat and layout are two sequential passes sharing buffers.
__global__ __launch_bounds__(TPB) void heat_loss_kernel(
    const float* __restrict__ layout, const float* __restrict__ heat,
    float* __restrict__ out) {
  const int b    = blockIdx.x;
  const int tid  = threadIdx.x;
  const int wave = tid >> 6;
  const int lane = tid & 63;

  __shared__ __align__(16) float4 s_colp[20][50];  // col-quad partials (16 KB)
  __shared__ float s_rowp[NXC][51];  // row-quad partials, pad 51
  __shared__ float s_CS[NXC];        // column sums heat
  __shared__ float s_CL[NXC];        // column sums layout
  __shared__ float s_RS[NXC];        // row sums heat
  __shared__ float s_RL[NXC];        // row sums layout
  __shared__ float s_red[4][16];     // minv/maxv/minh/maxh per wave
  __shared__ float s_sum[16];        // contrib partial per wave

  const f4* __restrict__ hp =
      reinterpret_cast<const f4*>(heat + (size_t)b * NXC * NXC);
  const f4* __restrict__ lp =
      reinterpret_cast<const f4*>(layout + (size_t)b * NXC * NXC);

  const int a = tid / 50;   // 0..19 for active threads
  const int c = tid % 50;

  // ---------------- pass 1: heat ----------------
  if (tid < NACT) {
    // issue ALL 10 loads back-to-back (independent addresses, named regs),
    // non-temporal: evict-first, don't re-allocate in LLC.
    const f4 v0 = __builtin_nontemporal_load(hp + tid +    0);
    const f4 v1 = __builtin_nontemporal_load(hp + tid + 1000);
    const f4 v2 = __builtin_nontemporal_load(hp + tid + 2000);
    const f4 v3 = __builtin_nontemporal_load(hp + tid + 3000);
    const f4 v4 = __builtin_nontemporal_load(hp + tid + 4000);
    const f4 v5 = __builtin_nontemporal_load(hp + tid + 5000);
    const f4 v6 = __builtin_nontemporal_load(hp + tid + 6000);
    const f4 v7 = __builtin_nontemporal_load(hp + tid + 7000);
    const f4 v8 = __builtin_nontemporal_load(hp + tid + 8000);
    const f4 v9 = __builtin_nontemporal_load(hp + tid + 9000);
    __builtin_amdgcn_sched_barrier(0);  // loads may not sink below this point

    s_rowp[a +   0][c] = (v0[0] + v0[1]) + (v0[2] + v0[3]);
    s_rowp[a +  20][c] = (v1[0] + v1[1]) + (v1[2] + v1[3]);
    s_rowp[a +  40][c] = (v2[0] + v2[1]) + (v2[2] + v2[3]);
    s_rowp[a +  60][c] = (v3[0] + v3[1]) + (v3[2] + v3[3]);
    s_rowp[a +  80][c] = (v4[0] + v4[1]) + (v4[2] + v4[3]);
    s_rowp[a + 100][c] = (v5[0] + v5[1]) + (v5[2] + v5[3]);
    s_rowp[a + 120][c] = (v6[0] + v6[1]) + (v6[2] + v6[3]);
    s_rowp[a + 140][c] = (v7[0] + v7[1]) + (v7[2] + v7[3]);
    s_rowp[a + 160][c] = (v8[0] + v8[1]) + (v8[2] + v8[3]);
    s_rowp[a + 180][c] = (v9[0] + v9[1]) + (v9[2] + v9[3]);

    const float cs0 = (((v0[0] + v1[0]) + (v2[0] + v3[0])) +
                       ((v4[0] + v5[0]) + (v6[0] + v7[0]))) + (v8[0] + v9[0]);
    const float cs1 = (((v0[1] + v1[1]) + (v2[1] + v3[1])) +
                       ((v4[1] + v5[1]) + (v6[1] + v7[1]))) + (v8[1] + v9[1]);
    const float cs2 = (((v0[2] + v1[2]) + (v2[2] + v3[2])) +
                       ((v4[2] + v5[2]) + (v6[2] + v7[2]))) + (v8[2] + v9[2]);
    const float cs3 = (((v0[3] + v1[3]) + (v2[3] + v3[3])) +
                       ((v4[3] + v5[3]) + (v6[3] + v7[3]))) + (v8[3] + v9[3]);
    s_colp[a][c] = make_float4(cs0, cs1, cs2, cs3);
  }
  __syncthreads();

  if (tid < NXC) {
    const float* cp = (const float*)s_colp;  // [a][200] flat view
    float s = 0.f;
    #pragma unroll
    for (int a2 = 0; a2 < 20; ++a2) s += cp[a2 * 200 + tid];
    float r = 0.f;
    #pragma unroll
    for (int m = 0; m < 50; ++m) r += s_rowp[tid][m];
    s_CS[tid] = s; s_RS[tid] = r;
  }
  __syncthreads();  // partial buffers now reusable

  // ---------------- pass 2: layout ----------------
  if (tid < NACT) {
    const f4 v0 = __builtin_nontemporal_load(lp + tid +    0);
    const f4 v1 = __builtin_nontemporal_load(lp + tid + 1000);
    const f4 v2 = __builtin_nontemporal_load(lp + tid + 2000);
    const f4 v3 = __builtin_nontemporal_load(lp + tid + 3000);
    const f4 v4 = __builtin_nontemporal_load(lp + tid + 4000);
    const f4 v5 = __builtin_nontemporal_load(lp + tid + 5000);
    const f4 v6 = __builtin_nontemporal_load(lp + tid + 6000);
    const f4 v7 = __builtin_nontemporal_load(lp + tid + 7000);
    const f4 v8 = __builtin_nontemporal_load(lp + tid + 8000);
    const f4 v9 = __builtin_nontemporal_load(lp + tid + 9000);
    __builtin_amdgcn_sched_barrier(0);

    s_rowp[a +   0][c] = (v0[0] + v0[1]) + (v0[2] + v0[3]);
    s_rowp[a +  20][c] = (v1[0] + v1[1]) + (v1[2] + v1[3]);
    s_rowp[a +  40][c] = (v2[0] + v2[1]) + (v2[2] + v2[3]);
    s_rowp[a +  60][c] = (v3[0] + v3[1]) + (v3[2] + v3[3]);
    s_rowp[a +  80][c] = (v4[0] + v4[1]) + (v4[2] + v4[3]);
    s_rowp[a + 100][c] = (v5[0] + v5[1]) + (v5[2] + v5[3]);
    s_rowp[a + 120][c] = (v6[0] + v6[1]) + (v6[2] + v6[3]);
    s_rowp[a + 140][c] = (v7[0] + v7[1]) + (v7[2] + v7[3]);
    s_rowp[a + 160][c] = (v8[0] + v8[1]) + (v8[2] + v8[3]);
    s_rowp[a + 180][c] = (v9[0] + v9[1]) + (v9[2] + v9[3]);

    const float cs0 = (((v0[0] + v1[0]) + (v2[0] + v3[0])) +
                       ((v4[0] + v5[0]) + (v6[0] + v7[0]))) + (v8[0] + v9[0]);
    const float cs1 = (((v0[1] + v1[1]) + (v2[1] + v3[1])) +
                       ((v4[1] + v5[1]) + (v6[1] + v7[1]))) + (v8[1] + v9[1]);
    const float cs2 = (((v0[2] + v1[2]) + (v2[2] + v3[2])) +
                       ((v4[2] + v5[2]) + (v6[2] + v7[2]))) + (v8[2] + v9[2]);
    const float cs3 = (((v0[3] + v1[3]) + (v2[3] + v3[3])) +
                       ((v4[3] + v5[3]) + (v6[3] + v7[3]))) + (v8[3] + v9[3]);
    s_colp[a][c] = make_float4(cs0, cs1, cs2, cs3);
  }
  __syncthreads();

  if (tid < NXC) {
    const float* cp = (const float*)s_colp;
    float s = 0.f;
    #pragma unroll
    for (int a2 = 0; a2 < 20; ++a2) s += cp[a2 * 200 + tid];
    float r = 0.f;
    #pragma unroll
    for (int m = 0; m < 50; ++m) r += s_rowp[tid][m];
    s_CL[tid] = s; s_RL[tid] = r;
  }
  __syncthreads();

  // ---------------- epilogue (verified exact in rounds 1-8) ----------------
  const float* __restrict__ hb = heat + (size_t)b * NXC * NXC;
  const float COF = (float)(0.25 * (0.1 / 199.0) * (0.1 / 199.0));
  float dv = 0.f, dh = 0.f;
  if (tid < NXC) {
    const int j  = tid;
    const int jm = (j == 0) ? 1 : j - 1;
    const int jp = (j == NXC - 1) ? NXC - 2 : j + 1;

    // boundary rows 0,1,198,199 (coalesced re-reads; normal cached loads)
    const float h0   = hb[0 * NXC + j];
    const float h1   = hb[1 * NXC + j];
    const float h198 = hb[198 * NXC + j];
    const float h199 = hb[199 * NXC + j];
    float Sv = 0.25f * (2.f * s_CS[j]
                        + h1 - h199        // +h[1,j]   - h[199,j]
                        + h198 - h0        // +h[198,j] - h[0,j]
                        + s_CS[jm] + s_CS[jp])
             + COF * s_CL[j];
    dv = fabsf(Sv - s_CS[j]) * (1.f / NXC);

    // boundary cols 0,1,198,199 of row j via two aligned float4 loads
    const float4 c03 = *reinterpret_cast<const float4*>(hb + (size_t)j * NXC);
    const float4 c69 = *reinterpret_cast<const float4*>(hb + (size_t)j * NXC + 196);
    float Sh = 0.25f * (2.f * s_RS[j]
                        + c03.y - c69.w    // +h[j,1]   - h[j,199]
                        + c69.z - c03.x    // +h[j,198] - h[j,0]
                        + s_RS[jm] + s_RS[jp])
             + COF * s_RL[j];
    dh = fabsf(Sh - s_RS[j]) * (1.f / NXC);
  }

  // per-batch min/max of dv and dh (dv,dh >= 0 so max pad 0 is safe)
  float mnv = (tid < NXC) ? dv : INFINITY;
  float mxv = dv;
  float mnh = (tid < NXC) ? dh : INFINITY;
  float mxh = dh;
  #pragma unroll
  for (int off = 32; off > 0; off >>= 1) {
    mnv = fminf(mnv, __shfl_down(mnv, off));
    mxv = fmaxf(mxv, __shfl_down(mxv, off));
    mnh = fminf(mnh, __shfl_down(mnh, off));
    mxh = fmaxf(mxh, __shfl_down(mxh, off));
  }
  if (lane == 0) {
    s_red[0][wave] = mnv;
    s_red[1][wave] = mxv;
    s_red[2][wave] = mnh;
    s_red[3][wave] = mxh;
  }
  __syncthreads();

  float MNV = INFINITY, MXV = -INFINITY, MNH = INFINITY, MXH = -INFINITY;
  #pragma unroll
  for (int w = 0; w < 16; ++w) {
    MNV = fminf(MNV, s_red[0][w]); MXV = fmaxf(MXV, s_red[1][w]);
    MNH = fminf(MNH, s_red[2][w]); MXH = fmaxf(MXH, s_red[3][w]);
  }

  float contrib = 0.f;
  if (tid < NXC) {
    contrib = 10.f * (dv - MNV) * dv / (MXV - MNV)
            + 10.f * (dh - MNH) * dh / (MXH - MNH);
  }
  #pragma unroll
  for (int off = 32; off > 0; off >>= 1) contrib += __shfl_down(contrib, off);
  if (lane == 0) s_sum[wave] = contrib;
  __syncthreads();
  if (tid == 0) {
    float tot = 0.f;
    #pragma unroll
    for (int w = 0; w < 16; ++w) tot += s_sum[w];
    atomicAdd(out, tot * (1.f / ((float)NBB * (float)NXC)));
  }
}

extern "C" void kernel_launch(void* const* d_in, const int* in_sizes, int n_in,
                              void* d_out, int out_size, void* d_ws, size_t ws_size,
                              hipStream_t stream) {
  const float* layout = (const float*)d_in[0];
  const float* heat   = (const float*)d_in[1];
  float* out = (float*)d_out;

  // d_out is poisoned to 0xAA before every timed launch — zero it first.
  hipMemsetAsync(out, 0, (size_t)out_size * sizeof(float), stream);
  heat_loss_kernel<<<NBB, TPB, 0, stream>>>(layout, heat, out);
}

// Round 11
// 171.623 us; speedup vs baseline: 1.0485x; 1.0006x over previous
//
#include <hip/hip_runtime.h>
#include <math.h>

#define NXC 200    // grid edge
#define NBB 512    // batch
#define TPB 1024   // threads per block (16 waves)
#define NACT 1000  // active threads in the streaming loop

typedef float f4 __attribute__((ext_vector_type(4)));

// Forced 10-deep non-temporal stream: one asm block issues all 10
// global_load_dwordx4 nt (saddr form: SGPR base + 32-bit voffset, bumped by
// v_add_u32 16000 between issues), then a single vmcnt(0). Ten distinct
// output tuples => 40 destination VGPRs provably co-resident => true MLP-10
// (r8 post-mortem: sched_barrier alone was ignored, VGPR stayed 32).
__device__ __forceinline__ void stream10_nt(
    const float* __restrict__ base, unsigned off,
    f4& v0, f4& v1, f4& v2, f4& v3, f4& v4,
    f4& v5, f4& v6, f4& v7, f4& v8, f4& v9) {
  asm volatile(
      "global_load_dwordx4 %[d0], %[off], %[b] nt\n\t"
      "v_add_u32 %[off], 0x3e80, %[off]\n\t"
      "global_load_dwordx4 %[d1], %[off], %[b] nt\n\t"
      "v_add_u32 %[off], 0x3e80, %[off]\n\t"
      "global_load_dwordx4 %[d2], %[off], %[b] nt\n\t"
      "v_add_u32 %[off], 0x3e80, %[off]\n\t"
      "global_load_dwordx4 %[d3], %[off], %[b] nt\n\t"
      "v_add_u32 %[off], 0x3e80, %[off]\n\t"
      "global_load_dwordx4 %[d4], %[off], %[b] nt\n\t"
      "v_add_u32 %[off], 0x3e80, %[off]\n\t"
      "global_load_dwordx4 %[d5], %[off], %[b] nt\n\t"
      "v_add_u32 %[off], 0x3e80, %[off]\n\t"
      "global_load_dwordx4 %[d6], %[off], %[b] nt\n\t"
      "v_add_u32 %[off], 0x3e80, %[off]\n\t"
      "global_load_dwordx4 %[d7], %[off], %[b] nt\n\t"
      "v_add_u32 %[off], 0x3e80, %[off]\n\t"
      "global_load_dwordx4 %[d8], %[off], %[b] nt\n\t"
      "v_add_u32 %[off], 0x3e80, %[off]\n\t"
      "global_load_dwordx4 %[d9], %[off], %[b] nt\n\t"
      "s_waitcnt vmcnt(0)\n\t"
      : [d0] "=&v"(v0), [d1] "=&v"(v1), [d2] "=&v"(v2), [d3] "=&v"(v3),
        [d4] "=&v"(v4), [d5] "=&v"(v5), [d6] "=&v"(v6), [d7] "=&v"(v7),
        [d8] "=&v"(v8), [d9] "=&v"(v9), [off] "+&v"(off)
      : [b] "s"(base)
      : "memory");
}

// One block per batch (512 blocks). Identical verified structure to round 9
// (index algebra, single-writer LDS partials, epilogue; absmax=0); the only
// change is the streaming loads go through stream10_nt above.
//
// Index algebra: thread t<1000 reads f = t + 1000k, k=0..9.
//   quad  c = t mod 50 (static), row = t/50 + 20k = a + 20k (static per k)
// -> col sums in 4 named registers; row quad-partials are single-writer LDS
//    stores; heat and layout are two sequential passes sharing buffers.
__global__ __launch_bounds__(TPB) void heat_loss_kernel(
    const float* __restrict__ layout, const float* __restrict__ heat,
    float* __restrict__ out) {
  const int b    = blockIdx.x;
  const int tid  = threadIdx.x;
  const int wave = tid >> 6;
  const int lane = tid & 63;

  __shared__ __align__(16) float4 s_colp[20][50];  // col-quad partials (16 KB)
  __shared__ float s_rowp[NXC][51];  // row-quad partials, pad 51
  __shared__ float s_CS[NXC];        // column sums heat
  __shared__ float s_CL[NXC];        // column sums layout
  __shared__ float s_RS[NXC];        // row sums heat
  __shared__ float s_RL[NXC];        // row sums layout
  __shared__ float s_red[4][16];     // minv/maxv/minh/maxh per wave
  __shared__ float s_sum[16];        // contrib partial per wave

  const float* hbase = heat   + (size_t)b * NXC * NXC;
  const float* lbase = layout + (size_t)b * NXC * NXC;

  const int a = tid / 50;   // 0..19 for active threads
  const int c = tid % 50;

  // ---------------- pass 1: heat ----------------
  if (tid < NACT) {
    f4 v0, v1, v2, v3, v4, v5, v6, v7, v8, v9;
    stream10_nt(hbase, (unsigned)tid * 16u,
                v0, v1, v2, v3, v4, v5, v6, v7, v8, v9);

    s_rowp[a +   0][c] = (v0[0] + v0[1]) + (v0[2] + v0[3]);
    s_rowp[a +  20][c] = (v1[0] + v1[1]) + (v1[2] + v1[3]);
    s_rowp[a +  40][c] = (v2[0] + v2[1]) + (v2[2] + v2[3]);
    s_rowp[a +  60][c] = (v3[0] + v3[1]) + (v3[2] + v3[3]);
    s_rowp[a +  80][c] = (v4[0] + v4[1]) + (v4[2] + v4[3]);
    s_rowp[a + 100][c] = (v5[0] + v5[1]) + (v5[2] + v5[3]);
    s_rowp[a + 120][c] = (v6[0] + v6[1]) + (v6[2] + v6[3]);
    s_rowp[a + 140][c] = (v7[0] + v7[1]) + (v7[2] + v7[3]);
    s_rowp[a + 160][c] = (v8[0] + v8[1]) + (v8[2] + v8[3]);
    s_rowp[a + 180][c] = (v9[0] + v9[1]) + (v9[2] + v9[3]);

    const float cs0 = (((v0[0] + v1[0]) + (v2[0] + v3[0])) +
                       ((v4[0] + v5[0]) + (v6[0] + v7[0]))) + (v8[0] + v9[0]);
    const float cs1 = (((v0[1] + v1[1]) + (v2[1] + v3[1])) +
                       ((v4[1] + v5[1]) + (v6[1] + v7[1]))) + (v8[1] + v9[1]);
    const float cs2 = (((v0[2] + v1[2]) + (v2[2] + v3[2])) +
                       ((v4[2] + v5[2]) + (v6[2] + v7[2]))) + (v8[2] + v9[2]);
    const float cs3 = (((v0[3] + v1[3]) + (v2[3] + v3[3])) +
                       ((v4[3] + v5[3]) + (v6[3] + v7[3]))) + (v8[3] + v9[3]);
    s_colp[a][c] = make_float4(cs0, cs1, cs2, cs3);
  }
  __syncthreads();

  if (tid < NXC) {
    const float* cp = (const float*)s_colp;  // [a][200] flat view
    float s = 0.f;
    #pragma unroll
    for (int a2 = 0; a2 < 20; ++a2) s += cp[a2 * 200 + tid];
    float r = 0.f;
    #pragma unroll
    for (int m = 0; m < 50; ++m) r += s_rowp[tid][m];
    s_CS[tid] = s; s_RS[tid] = r;
  }
  __syncthreads();  // partial buffers now reusable

  // ---------------- pass 2: layout ----------------
  if (tid < NACT) {
    f4 v0, v1, v2, v3, v4, v5, v6, v7, v8, v9;
    stream10_nt(lbase, (unsigned)tid * 16u,
                v0, v1, v2, v3, v4, v5, v6, v7, v8, v9);

    s_rowp[a +   0][c] = (v0[0] + v0[1]) + (v0[2] + v0[3]);
    s_rowp[a +  20][c] = (v1[0] + v1[1]) + (v1[2] + v1[3]);
    s_rowp[a +  40][c] = (v2[0] + v2[1]) + (v2[2] + v2[3]);
    s_rowp[a +  60][c] = (v3[0] + v3[1]) + (v3[2] + v3[3]);
    s_rowp[a +  80][c] = (v4[0] + v4[1]) + (v4[2] + v4[3]);
    s_rowp[a + 100][c] = (v5[0] + v5[1]) + (v5[2] + v5[3]);
    s_rowp[a + 120][c] = (v6[0] + v6[1]) + (v6[2] + v6[3]);
    s_rowp[a + 140][c] = (v7[0] + v7[1]) + (v7[2] + v7[3]);
    s_rowp[a + 160][c] = (v8[0] + v8[1]) + (v8[2] + v8[3]);
    s_rowp[a + 180][c] = (v9[0] + v9[1]) + (v9[2] + v9[3]);

    const float cs0 = (((v0[0] + v1[0]) + (v2[0] + v3[0])) +
                       ((v4[0] + v5[0]) + (v6[0] + v7[0]))) + (v8[0] + v9[0]);
    const float cs1 = (((v0[1] + v1[1]) + (v2[1] + v3[1])) +
                       ((v4[1] + v5[1]) + (v6[1] + v7[1]))) + (v8[1] + v9[1]);
    const float cs2 = (((v0[2] + v1[2]) + (v2[2] + v3[2])) +
                       ((v4[2] + v5[2]) + (v6[2] + v7[2]))) + (v8[2] + v9[2]);
    const float cs3 = (((v0[3] + v1[3]) + (v2[3] + v3[3])) +
                       ((v4[3] + v5[3]) + (v6[3] + v7[3]))) + (v8[3] + v9[3]);
    s_colp[a][c] = make_float4(cs0, cs1, cs2, cs3);
  }
  __syncthreads();

  if (tid < NXC) {
    const float* cp = (const float*)s_colp;
    float s = 0.f;
    #pragma unroll
    for (int a2 = 0; a2 < 20; ++a2) s += cp[a2 * 200 + tid];
    float r = 0.f;
    #pragma unroll
    for (int m = 0; m < 50; ++m) r += s_rowp[tid][m];
    s_CL[tid] = s; s_RL[tid] = r;
  }
  __syncthreads();

  // ---------------- epilogue (verified exact in rounds 1-9) ----------------
  const float* __restrict__ hb = heat + (size_t)b * NXC * NXC;
  const float COF = (float)(0.25 * (0.1 / 199.0) * (0.1 / 199.0));
  float dv = 0.f, dh = 0.f;
  if (tid < NXC) {
    const int j  = tid;
    const int jm = (j == 0) ? 1 : j - 1;
    const int jp = (j == NXC - 1) ? NXC - 2 : j + 1;

    // boundary rows 0,1,198,199 (coalesced re-reads; normal cached loads)
    const float h0   = hb[0 * NXC + j];
    const float h1   = hb[1 * NXC + j];
    const float h198 = hb[198 * NXC + j];
    const float h199 = hb[199 * NXC + j];
    float Sv = 0.25f * (2.f * s_CS[j]
                        + h1 - h199        // +h[1,j]   - h[199,j]
                        + h198 - h0        // +h[198,j] - h[0,j]
                        + s_CS[jm] + s_CS[jp])
             + COF * s_CL[j];
    dv = fabsf(Sv - s_CS[j]) * (1.f / NXC);

    // boundary cols 0,1,198,199 of row j via two aligned float4 loads
    const float4 c03 = *reinterpret_cast<const float4*>(hb + (size_t)j * NXC);
    const float4 c69 = *reinterpret_cast<const float4*>(hb + (size_t)j * NXC + 196);
    float Sh = 0.25f * (2.f * s_RS[j]
                        + c03.y - c69.w    // +h[j,1]   - h[j,199]
                        + c69.z - c03.x    // +h[j,198] - h[j,0]
                        + s_RS[jm] + s_RS[jp])
             + COF * s_RL[j];
    dh = fabsf(Sh - s_RS[j]) * (1.f / NXC);
  }

  // per-batch min/max of dv and dh (dv,dh >= 0 so max pad 0 is safe)
  float mnv = (tid < NXC) ? dv : INFINITY;
  float mxv = dv;
  float mnh = (tid < NXC) ? dh : INFINITY;
  float mxh = dh;
  #pragma unroll
  for (int off = 32; off > 0; off >>= 1) {
    mnv = fminf(mnv, __shfl_down(mnv, off));
    mxv = fmaxf(mxv, __shfl_down(mxv, off));
    mnh = fminf(mnh, __shfl_down(mnh, off));
    mxh = fmaxf(mxh, __shfl_down(mxh, off));
  }
  if (lane == 0) {
    s_red[0][wave] = mnv;
    s_red[1][wave] = mxv;
    s_red[2][wave] = mnh;
    s_red[3][wave] = mxh;
  }
  __syncthreads();

  float MNV = INFINITY, MXV = -INFINITY, MNH = INFINITY, MXH = -INFINITY;
  #pragma unroll
  for (int w = 0; w < 16; ++w) {
    MNV = fminf(MNV, s_red[0][w]); MXV = fmaxf(MXV, s_red[1][w]);
    MNH = fminf(MNH, s_red[2][w]); MXH = fmaxf(MXH, s_red[3][w]);
  }

  float contrib = 0.f;
  if (tid < NXC) {
    contrib = 10.f * (dv - MNV) * dv / (MXV - MNV)
            + 10.f * (dh - MNH) * dh / (MXH - MNH);
  }
  #pragma unroll
  for (int off = 32; off > 0; off >>= 1) contrib += __shfl_down(contrib, off);
  if (lane == 0) s_sum[wave] = contrib;
  __syncthreads();
  if (tid == 0) {
    float tot = 0.f;
    #pragma unroll
    for (int w = 0; w < 16; ++w) tot += s_sum[w];
    atomicAdd(out, tot * (1.f / ((float)NBB * (float)NXC)));
  }
}

extern "C" void kernel_launch(void* const* d_in, const int* in_sizes, int n_in,
                              void* d_out, int out_size, void* d_ws, size_t ws_size,
                              hipStream_t stream) {
  const float* layout = (const float*)d_in[0];
  const float* heat   = (const float*)d_in[1];
  float* out = (float*)d_out;

  // d_out is poisoned to 0xAA before every timed launch — zero it first.
  hipMemsetAsync(out, 0, (size_t)out_size * sizeof(float), stream);
  heat_loss_kernel<<<NBB, TPB, 0, stream>>>(layout, heat, out);
}